// Round 9
// baseline (236.534 us; speedup 1.0000x reference)
//
#include <hip/hip_runtime.h>
#include <math.h>

#define DD 128
#define CAP 10240
typedef unsigned int u32;
typedef unsigned short u16;
typedef __attribute__((ext_vector_type(8))) short bf16x8;
typedef __attribute__((ext_vector_type(4))) float f32x4;
typedef __attribute__((ext_vector_type(2))) float f32x2;

__device__ __forceinline__ float4 f4zero() { return make_float4(0.f, 0.f, 0.f, 0.f); }
// round-to-nearest-even f32 -> bf16 (low 16 bits)
__device__ __forceinline__ u32 bf16rne(float f) {
    u32 u = __float_as_uint(f);
    u += 0x7FFFu + ((u >> 16) & 1u);
    return u >> 16;
}
__device__ __forceinline__ u32 pack2(float lo, float hi) {
    return bf16rne(lo) | (bf16rne(hi) << 16);
}
__device__ __forceinline__ float unlo(u32 u) { return __uint_as_float(u << 16); }
__device__ __forceinline__ float unhi(u32 u) { return __uint_as_float(u & 0xFFFF0000u); }

// ---------------------------------------------------------------------------
// compose_frags: weights into MFMA B-fragment order (bf16). 38 blocks x 256
// (4 sub-bids of 64 lanes each). Verified.
// ---------------------------------------------------------------------------
__global__ __launch_bounds__(256) void compose_frags(
    const float* __restrict__ Wq, const float* __restrict__ Wk,
    const float* __restrict__ Wv, const float* __restrict__ We1,
    const float* __restrict__ be1, const float* __restrict__ Wp2,
    const float* __restrict__ bp2, const float* __restrict__ Wo,
    u32* __restrict__ BF) {
    const int t = threadIdx.x;
    const int bid = blockIdx.x * 4 + (t >> 6);
    const int l = t & 63;
    const int c = l & 15;
    const int kg = l >> 4;
    float val[8];

    if (bid < 120) {
        const int ct = bid / 5, ks = bid - ct * 5;
        const int u = ct / 6, r = ct - u * 6;
        const int n = 32 * u + 16 * (r < 2 ? r : (r & 1)) + c;
#pragma unroll
        for (int j = 0; j < 8; ++j) {
            const int k = ks * 32 + kg * 8 + j;
            float v = 0.f;
            if (r < 2) {  // Q section
                if (k < 128) {
                    float a = 0.f;
                    for (int q = 0; q < 128; ++q)
                        a = fmaf(Wq[k * 128 + q], We1[q * 128 + n], a);
                    v = a;
                }
            } else if (r < 4) {  // K section
                if (k < 128) {
                    float a = 0.f;
                    for (int q = 0; q < 128; ++q)
                        a = fmaf(Wk[k * 128 + q], We1[q * 128 + n], a);
                    v = a;
                } else if (k < 131) {
                    float a = 0.f;
                    for (int q = 0; q < 128; ++q)
                        a = fmaf(Wp2[(k - 128) * 128 + q], We1[q * 128 + n], a);
                    v = a;
                } else if (k == 131) {
                    float a = be1[n];
                    for (int q = 0; q < 128; ++q)
                        a = fmaf(bp2[q], We1[q * 128 + n], a);
                    v = a;
                }
            } else {  // V section
                if (k < 128) v = Wv[k * 128 + n];
                else if (k < 131) v = Wp2[(k - 128) * 128 + n];
                else if (k == 131) v = bp2[n];
            }
            val[j] = v;
        }
    } else {  // Wo fragments
        const int b2 = bid - 120;
        const int ct = b2 >> 2, ks = b2 & 3;
        const int n = ct * 16 + c;
#pragma unroll
        for (int j = 0; j < 8; ++j) {
            const int k = ks * 32 + kg * 8 + j;
            val[j] = Wo[k * 128 + n];
        }
    }
    u32* dp = &BF[((size_t)bid * 64 + l) * 4];
    dp[0] = pack2(val[0], val[1]);
    dp[1] = pack2(val[2], val[3]);
    dp[2] = pack2(val[4], val[5]);
    dp[3] = pack2(val[6], val[7]);
}

// ---------------------------------------------------------------------------
// fused_p1_gemm: blocks [0,NB1) = p1 edge bucketing; rest = node MFMA GEMM.
// GEMM epilogue: QWb bf16-pair, Kb8 fp8, Vb bf16-pair.
// ---------------------------------------------------------------------------
__global__ __launch_bounds__(256) void fused_p1_gemm(
    const float* __restrict__ h, const float* __restrict__ c,
    const float* __restrict__ Wp1, const float* __restrict__ bp1,
    const u32* __restrict__ BF,
    u32* __restrict__ QWb, unsigned char* __restrict__ Kb8,
    u32* __restrict__ Vb, int N,
    const int* __restrict__ src, const int* __restrict__ dst,
    int* __restrict__ gcount, u32* __restrict__ ebuf, int E, int NB1) {
    __shared__ u32 lds[64 * 96];  // 24 KB, aliased by both paths
    const int t = threadIdx.x;

    if ((int)blockIdx.x < NB1) {
        // ---- p1: LDS-ranked coarse bucket (dst>>9) ----
        int* hist = (int*)lds;
        int* base = hist + 256;
        hist[t] = 0;
        __syncthreads();
        const int chunk = blockIdx.x * 4096;
        int bk[16], rk[16];
        u32 pv[16];
#pragma unroll
        for (int i = 0; i < 16; ++i) {
            int idx = chunk + i * 256 + t;
            bk[i] = -1;
            if (idx < E) {
                int dd = dst[idx];
                int ss = src[idx];
                bk[i] = dd >> 9;
                pv[i] = ((u32)ss << 9) | (u32)(dd & 511);
                rk[i] = atomicAdd(&hist[bk[i]], 1);
            }
        }
        __syncthreads();
        if (hist[t]) base[t] = t * CAP + atomicAdd(&gcount[t], hist[t]);
        __syncthreads();
#pragma unroll
        for (int i = 0; i < 16; ++i) {
            if (bk[i] >= 0) ebuf[base[bk[i]] + rk[i]] = pv[i];
        }
    } else {
        // ---- node_mfma: [N x 160] @ [160 x 384] bf16 MFMA GEMM ----
        u32* hs = lds;
        const int row0 = ((int)blockIdx.x - NB1) * 64;

#pragma unroll
        for (int i = 0; i < 8; ++i) {
            int f = t + i * 256;
            int row = f >> 5;
            int cq = f & 31;
            float4 v = f4zero();
            if (row0 + row < N) v = *(const float4*)&h[(size_t)(row0 + row) * DD + cq * 4];
            int idx = row * 96 + ((cq * 2) ^ ((row & 7) << 2));
            uint2 p;
            p.x = pack2(v.x, v.y);
            p.y = pack2(v.z, v.w);
            *(uint2*)&hs[idx] = p;
        }
        if (t < 64) {
            int row = t;
            float u0 = 0.f, u1 = 0.f, u2 = 0.f;
            if (row0 + row < N) {
                const float* cr = &c[(size_t)(row0 + row) * 3];
                float c0 = cr[0], c1 = cr[1], c2 = cr[2];
                u0 = fmaxf(bp1[0] + c0 * Wp1[0] + c1 * Wp1[3] + c2 * Wp1[6], 0.f);
                u1 = fmaxf(bp1[1] + c0 * Wp1[1] + c1 * Wp1[4] + c2 * Wp1[7], 0.f);
                u2 = fmaxf(bp1[2] + c0 * Wp1[2] + c1 * Wp1[5] + c2 * Wp1[8], 0.f);
            }
            int swz = (row & 7) << 2;
            uint4 z0 = make_uint4(pack2(u0, u1), pack2(u2, 1.0f), 0u, 0u);
            uint4 zz = make_uint4(0u, 0u, 0u, 0u);
#pragma unroll
            for (int q = 0; q < 4; ++q) {
                int idx = row * 96 + 64 + ((q * 4) ^ swz);
                *(uint4*)&hs[idx] = (q == 0) ? z0 : zz;
            }
        }
        __syncthreads();

        const int w = t >> 6, l = t & 63;
        const int cc = l & 15, kg = l >> 4;

        f32x4 acc[4][6];
#pragma unroll
        for (int rt = 0; rt < 4; ++rt)
#pragma unroll
            for (int r = 0; r < 6; ++r) acc[rt][r] = (f32x4){0.f, 0.f, 0.f, 0.f};

#pragma unroll
        for (int ks = 0; ks < 5; ++ks) {
            bf16x8 a[4];
#pragma unroll
            for (int rt = 0; rt < 4; ++rt) {
                int row = rt * 16 + cc;
                int idx = row * 96 + ((ks * 16 + kg * 4) ^ ((row & 7) << 2));
                a[rt] = *(const bf16x8*)&hs[idx];
            }
#pragma unroll
            for (int r = 0; r < 6; ++r) {
                const bf16x8 b = *(const bf16x8*)&BF[(((size_t)(w * 6 + r) * 5 + ks) * 64 + l) * 4];
#pragma unroll
                for (int rt = 0; rt < 4; ++rt)
                    acc[rt][r] = __builtin_amdgcn_mfma_f32_16x16x32_bf16(a[rt], b, acc[rt][r], 0, 0, 0);
            }
        }

#pragma unroll
        for (int rt = 0; rt < 4; ++rt) {
#pragma unroll
            for (int j = 0; j < 4; ++j) {
                int row = row0 + rt * 16 + kg * 4 + j;
                if (row >= N) continue;
                QWb[(size_t)row * 64 + w * 16 + cc] = pack2(acc[rt][0][j], acc[rt][1][j]);
                u32 kp = __builtin_amdgcn_cvt_pk_fp8_f32(acc[rt][2][j], acc[rt][3][j], 0u, false);
                *(u16*)&Kb8[(size_t)row * 128 + w * 32 + cc * 2] = (u16)kp;
                Vb[(size_t)row * 64 + w * 16 + cc] = pack2(acc[rt][4][j], acc[rt][5][j]);
            }
        }
    }
}

// ---------------------------------------------------------------------------
// scanB + We2 reorder into slot order.
// ---------------------------------------------------------------------------
__global__ __launch_bounds__(256) void scanB_we2r(
    const int* __restrict__ gcount, int* __restrict__ bucket_base,
    const float* __restrict__ We2, float* __restrict__ We2r) {
    __shared__ int s[256];
    int t = threadIdx.x;
    int orig = gcount[t];
    s[t] = orig;
    __syncthreads();
    for (int off = 1; off < 256; off <<= 1) {
        int x = (t >= off) ? s[t - off] : 0;
        __syncthreads();
        s[t] += x;
        __syncthreads();
    }
    bucket_base[t] = s[t] - orig;
    if (t < 128) {
        int col = 32 * (t >> 5) + 16 * (t & 1) + ((t & 31) >> 1);
        We2r[t] = We2[col];
    }
}

// ---------------------------------------------------------------------------
// p2_local: per-bucket CSR finalize (one block per 512-node bucket).
// ---------------------------------------------------------------------------
__global__ __launch_bounds__(256) void p2_local(
    const int* __restrict__ gcount, const int* __restrict__ bucket_base,
    const u32* __restrict__ ebuf, int* __restrict__ ssrc,
    int* __restrict__ offs, int E, int NR) {
    __shared__ int cnt[512];
    __shared__ int cur[512];
    __shared__ int ts[256];
    const int r = blockIdx.x;
    const int t = threadIdx.x;
    const int cnt_r = gcount[r];
    const int base_r = bucket_base[r];
    cnt[t] = 0;
    cnt[t + 256] = 0;
    __syncthreads();
    const u32* eb = &ebuf[(size_t)r * CAP];
    for (int i = t; i < cnt_r; i += 256) atomicAdd(&cnt[eb[i] & 511], 1);
    __syncthreads();
    int v0 = cnt[2 * t], v1 = cnt[2 * t + 1];
    int pair = v0 + v1;
    ts[t] = pair;
    __syncthreads();
    for (int off = 1; off < 256; off <<= 1) {
        int x = (t >= off) ? ts[t - off] : 0;
        __syncthreads();
        ts[t] += x;
        __syncthreads();
    }
    int ex = ts[t] - pair;
    cur[2 * t] = ex;
    cur[2 * t + 1] = ex + v0;
    offs[r * 512 + 2 * t] = base_r + ex;
    offs[r * 512 + 2 * t + 1] = base_r + ex + v0;
    if (r == NR - 1 && t == 255) offs[NR * 512] = E;
    __syncthreads();
    for (int i = t; i < cnt_r; i += 256) {
        u32 e = eb[i];
        int p = atomicAdd(&cur[e & 511], 1);
        ssrc[base_r + p] = (int)(e >> 9);
    }
}

// ---------------------------------------------------------------------------
// Aggregate: 8-lane groups (8 edges in flight/wave); fp8 K (16 B/lane) +
// bf16 V (32 B/lane). Lane i of group g owns slots 16i..16i+15.
// ---------------------------------------------------------------------------
__global__ __launch_bounds__(256) void aggregate(
    const int* __restrict__ offs, const int* __restrict__ ssrc,
    const unsigned char* __restrict__ Kb8, const u32* __restrict__ Vb,
    const u32* __restrict__ QWb, const float* __restrict__ We2r,
    const float* __restrict__ be2, u32* __restrict__ headb, int N) {
    const int node = (blockIdx.x * 256 + threadIdx.x) >> 6;
    const int lane = threadIdx.x & 63;
    if (node >= N) return;
    const int g = lane >> 3, i = lane & 7;

    const float SC = 0.08838834764831845f * 1.4426950408889634f;  // (1/sqrt128)*log2e
    const float CL = 5.0f * 1.4426950408889634f;

    uint4 QA = *(const uint4*)&QWb[(size_t)node * 64 + 8 * i];
    uint4 QB = *(const uint4*)&QWb[(size_t)node * 64 + 8 * i + 4];
    float q[16];
    q[0] = unlo(QA.x); q[1] = unhi(QA.x); q[2] = unlo(QA.y); q[3] = unhi(QA.y);
    q[4] = unlo(QA.z); q[5] = unhi(QA.z); q[6] = unlo(QA.w); q[7] = unhi(QA.w);
    q[8] = unlo(QB.x); q[9] = unhi(QB.x); q[10] = unlo(QB.y); q[11] = unhi(QB.y);
    q[12] = unlo(QB.z); q[13] = unhi(QB.z); q[14] = unlo(QB.w); q[15] = unhi(QB.w);

    float4 w0 = *(const float4*)&We2r[16 * i];
    float4 w1 = *(const float4*)&We2r[16 * i + 4];
    float4 w2 = *(const float4*)&We2r[16 * i + 8];
    float4 w3 = *(const float4*)&We2r[16 * i + 12];
    float w[16] = {w0.x, w0.y, w0.z, w0.w, w1.x, w1.y, w1.z, w1.w,
                   w2.x, w2.y, w2.z, w2.w, w3.x, w3.y, w3.z, w3.w};
    float b2 = be2[0];

    const int beg = offs[node], end = offs[node + 1];
    float acc[16];
#pragma unroll
    for (int j = 0; j < 16; ++j) acc[j] = 0.f;
    float zacc = 0.f;

    int e = beg + g;
    int s = (e < end) ? ssrc[e] : 0;
    for (int e0 = beg; e0 < end; e0 += 8) {
        const bool act = (e0 + g) < end;
        const int scur = s;
        const int en = e0 + 8 + g;
        s = (en < end) ? ssrc[en] : 0;  // prefetch next group edge

        uint4 kk = *(const uint4*)&Kb8[(size_t)scur * 128 + 16 * i];
        uint4 va = *(const uint4*)&Vb[(size_t)scur * 64 + 8 * i];
        uint4 vb = *(const uint4*)&Vb[(size_t)scur * 64 + 8 * i + 4];

        float kd[16];
        f32x2 tt;
        tt = __builtin_amdgcn_cvt_pk_f32_fp8(kk.x, false); kd[0] = tt[0]; kd[1] = tt[1];
        tt = __builtin_amdgcn_cvt_pk_f32_fp8(kk.x, true);  kd[2] = tt[0]; kd[3] = tt[1];
        tt = __builtin_amdgcn_cvt_pk_f32_fp8(kk.y, false); kd[4] = tt[0]; kd[5] = tt[1];
        tt = __builtin_amdgcn_cvt_pk_f32_fp8(kk.y, true);  kd[6] = tt[0]; kd[7] = tt[1];
        tt = __builtin_amdgcn_cvt_pk_f32_fp8(kk.z, false); kd[8] = tt[0]; kd[9] = tt[1];
        tt = __builtin_amdgcn_cvt_pk_f32_fp8(kk.z, true);  kd[10] = tt[0]; kd[11] = tt[1];
        tt = __builtin_amdgcn_cvt_pk_f32_fp8(kk.w, false); kd[12] = tt[0]; kd[13] = tt[1];
        tt = __builtin_amdgcn_cvt_pk_f32_fp8(kk.w, true);  kd[14] = tt[0]; kd[15] = tt[1];

        float p = fmaxf(kd[0] - q[0], 0.f) * w[0];
#pragma unroll
        for (int j = 1; j < 16; ++j) p = fmaf(fmaxf(kd[j] - q[j], 0.f), w[j], p);
#pragma unroll
        for (int off = 1; off <= 4; off <<= 1) p += __shfl_xor(p, off);

        float targ = (p + b2) * SC;
        targ = fminf(fmaxf(targ, -CL), CL);
        float sc = act ? exp2f(targ) : 0.f;

        acc[0]  = fmaf(unlo(va.x), sc, acc[0]);
        acc[1]  = fmaf(unhi(va.x), sc, acc[1]);
        acc[2]  = fmaf(unlo(va.y), sc, acc[2]);
        acc[3]  = fmaf(unhi(va.y), sc, acc[3]);
        acc[4]  = fmaf(unlo(va.z), sc, acc[4]);
        acc[5]  = fmaf(unhi(va.z), sc, acc[5]);
        acc[6]  = fmaf(unlo(va.w), sc, acc[6]);
        acc[7]  = fmaf(unhi(va.w), sc, acc[7]);
        acc[8]  = fmaf(unlo(vb.x), sc, acc[8]);
        acc[9]  = fmaf(unhi(vb.x), sc, acc[9]);
        acc[10] = fmaf(unlo(vb.y), sc, acc[10]);
        acc[11] = fmaf(unhi(vb.y), sc, acc[11]);
        acc[12] = fmaf(unlo(vb.z), sc, acc[12]);
        acc[13] = fmaf(unhi(vb.z), sc, acc[13]);
        acc[14] = fmaf(unlo(vb.w), sc, acc[14]);
        acc[15] = fmaf(unhi(vb.w), sc, acc[15]);
        zacc += sc;
    }

    // combine across the 8 groups
#pragma unroll
    for (int off = 8; off <= 32; off <<= 1) {
#pragma unroll
        for (int j = 0; j < 16; ++j) acc[j] += __shfl_xor(acc[j], off);
        zacc += __shfl_xor(zacc, off);
    }

    if (g == 0) {
        float rz = 1.0f / zacc;
        uint4 oA, oB;
        oA.x = pack2(acc[0] * rz, acc[1] * rz);
        oA.y = pack2(acc[2] * rz, acc[3] * rz);
        oA.z = pack2(acc[4] * rz, acc[5] * rz);
        oA.w = pack2(acc[6] * rz, acc[7] * rz);
        oB.x = pack2(acc[8] * rz, acc[9] * rz);
        oB.y = pack2(acc[10] * rz, acc[11] * rz);
        oB.z = pack2(acc[12] * rz, acc[13] * rz);
        oB.w = pack2(acc[14] * rz, acc[15] * rz);
        *(uint4*)&headb[(size_t)node * 64 + 8 * i] = oA;
        *(uint4*)&headb[(size_t)node * 64 + 8 * i + 4] = oB;
    }
}

// ---------------------------------------------------------------------------
// out = head @ Wo + bo via MFMA (unchanged — verified).
// ---------------------------------------------------------------------------
__global__ __launch_bounds__(256) void out_mfma(
    const u32* __restrict__ headb, const u32* __restrict__ WoF,
    const float* __restrict__ bo, float* __restrict__ out, int N) {
    __shared__ u32 hs[64 * 64];

    const int row0 = blockIdx.x * 64;
    const int t = threadIdx.x;

#pragma unroll
    for (int i = 0; i < 4; ++i) {
        int f = t + i * 256;
        int row = f >> 4;
        int cq = f & 15;
        uint4 v = make_uint4(0u, 0u, 0u, 0u);
        if (row0 + row < N) v = *(const uint4*)&headb[(size_t)(row0 + row) * 64 + cq * 4];
        int m = cq >> 2;
        int cb = (cq & 3) * 4;
        int swz = (row & 7) << 2;
        uint2 A, B;
        A.x = (v.x & 0xFFFFu) | (v.y << 16);
        A.y = (v.z & 0xFFFFu) | (v.w << 16);
        B.x = (v.x >> 16) | (v.y & 0xFFFF0000u);
        B.y = (v.z >> 16) | (v.w & 0xFFFF0000u);
        int dA = 16 * m + (cb >> 1);
        *(uint2*)&hs[row * 64 + (dA ^ swz)] = A;
        *(uint2*)&hs[row * 64 + ((dA + 8) ^ swz)] = B;
    }
    __syncthreads();

    const int w = t >> 6, l = t & 63;
    const int cc = l & 15, kg = l >> 4;

    f32x4 acc[4][2];
#pragma unroll
    for (int rt = 0; rt < 4; ++rt) {
        acc[rt][0] = (f32x4){0.f, 0.f, 0.f, 0.f};
        acc[rt][1] = (f32x4){0.f, 0.f, 0.f, 0.f};
    }

#pragma unroll
    for (int ks = 0; ks < 4; ++ks) {
        bf16x8 a[4];
#pragma unroll
        for (int rt = 0; rt < 4; ++rt) {
            int row = rt * 16 + cc;
            int idx = row * 64 + ((ks * 16 + kg * 4) ^ ((row & 7) << 2));
            a[rt] = *(const bf16x8*)&hs[idx];
        }
#pragma unroll
        for (int ctl = 0; ctl < 2; ++ctl) {
            const bf16x8 b = *(const bf16x8*)&WoF[(((size_t)(2 * w + ctl) * 4 + ks) * 64 + l) * 4];
#pragma unroll
            for (int rt = 0; rt < 4; ++rt)
                acc[rt][ctl] = __builtin_amdgcn_mfma_f32_16x16x32_bf16(a[rt], b, acc[rt][ctl], 0, 0, 0);
        }
    }

#pragma unroll
    for (int ctl = 0; ctl < 2; ++ctl) {
        int col = (2 * w + ctl) * 16 + cc;
        float bias = bo[col];
#pragma unroll
        for (int rt = 0; rt < 4; ++rt) {
#pragma unroll
            for (int j = 0; j < 4; ++j) {
                int row = row0 + rt * 16 + kg * 4 + j;
                if (row >= N) continue;
                out[(size_t)row * DD + col] = acc[rt][ctl][j] + bias;
            }
        }
    }
}

// ---------------------------------------------------------------------------
extern "C" void kernel_launch(void* const* d_in, const int* in_sizes, int n_in,
                              void* d_out, int out_size, void* d_ws, size_t ws_size,
                              hipStream_t stream) {
    const float* h   = (const float*)d_in[0];
    const float* c   = (const float*)d_in[1];
    const int*   src = (const int*)d_in[2];
    const int*   dst = (const int*)d_in[3];
    const float* Wq  = (const float*)d_in[4];
    const float* Wk  = (const float*)d_in[5];
    const float* Wv  = (const float*)d_in[6];
    const float* Wp1 = (const float*)d_in[7];
    const float* bp1 = (const float*)d_in[8];
    const float* Wp2 = (const float*)d_in[9];
    const float* bp2 = (const float*)d_in[10];
    const float* We1 = (const float*)d_in[11];
    const float* be1 = (const float*)d_in[12];
    const float* We2 = (const float*)d_in[13];
    const float* be2 = (const float*)d_in[14];
    const float* Wo  = (const float*)d_in[15];
    const float* bo  = (const float*)d_in[16];

    const int N = in_sizes[0] / DD;
    const int E = in_sizes[2];
    const int NR = (N + 511) >> 9;        // 512-node buckets
    const int NB1 = (E + 4095) / 4096;    // p1 blocks
    const int NG = (N + 63) / 64;         // GEMM blocks

    u32* BF    = (u32*)d_ws;                       // 152*256
    u32* WoF   = BF + 120 * 256;
    u32* QWb   = BF + 152 * 256;                   // N*64 u32
    unsigned char* Kb8 = (unsigned char*)(QWb + (size_t)N * 64);  // N*128 B
    u32* Vb    = (u32*)(Kb8 + (size_t)N * 128);    // N*64 u32
    u32* headb = Vb + (size_t)N * 64;              // N*64 u32
    int* offs  = (int*)(headb + (size_t)N * 64);   // NR*512+1
    int* gcount = offs + ((size_t)NR * 512 + 1);   // 256
    int* bbase  = gcount + 256;                    // 256
    float* We2r = (float*)(bbase + 256);           // 128
    int* ssrc   = (int*)(We2r + 128);              // E
    u32* ebuf   = (u32*)(ssrc + E);                // 256*CAP

    hipMemsetAsync(gcount, 0, 256 * sizeof(int), stream);

    compose_frags<<<38, 256, 0, stream>>>(Wq, Wk, Wv, We1, be1, Wp2, bp2, Wo, BF);

    fused_p1_gemm<<<NB1 + NG, 256, 0, stream>>>(
        h, c, Wp1, bp1, BF, QWb, Kb8, Vb, N,
        src, dst, gcount, ebuf, E, NB1);

    scanB_we2r<<<1, 256, 0, stream>>>(gcount, bbase, We2, We2r);

    p2_local<<<NR, 256, 0, stream>>>(gcount, bbase, ebuf, ssrc, offs, E, NR);

    aggregate<<<(N * 64 + 255) / 256, 256, 0, stream>>>(offs, ssrc, Kb8, Vb,
                                                        QWb, We2r, be2, headb, N);

    out_mfma<<<NG, 256, 0, stream>>>(headb, WoF, bo, (float*)d_out, N);
}

// Round 10
// 212.695 us; speedup vs baseline: 1.1121x; 1.1121x over previous
//
#include <hip/hip_runtime.h>
#include <math.h>

#define DD 128
#define CAP 10240
typedef unsigned int u32;
typedef unsigned short u16;
typedef __attribute__((ext_vector_type(8))) short bf16x8;
typedef __attribute__((ext_vector_type(4))) float f32x4;
typedef __attribute__((ext_vector_type(2))) float f32x2;

__device__ __forceinline__ float4 f4zero() { return make_float4(0.f, 0.f, 0.f, 0.f); }
// round-to-nearest-even f32 -> bf16 (low 16 bits)
__device__ __forceinline__ u32 bf16rne(float f) {
    u32 u = __float_as_uint(f);
    u += 0x7FFFu + ((u >> 16) & 1u);
    return u >> 16;
}
__device__ __forceinline__ u32 pack2(float lo, float hi) {
    return bf16rne(lo) | (bf16rne(hi) << 16);
}
__device__ __forceinline__ float unlo(u32 u) { return __uint_as_float(u << 16); }
__device__ __forceinline__ float unhi(u32 u) { return __uint_as_float(u & 0xFFFF0000u); }

// ---------------------------------------------------------------------------
// Fused pre: compose_frags (blocks 0..37, 4 sub-bids each) || p1_bucket.
// (R7-verified structure)
// ---------------------------------------------------------------------------
__global__ __launch_bounds__(256) void fused_pre(
    const float* __restrict__ Wq, const float* __restrict__ Wk,
    const float* __restrict__ Wv, const float* __restrict__ We1,
    const float* __restrict__ be1, const float* __restrict__ Wp2,
    const float* __restrict__ bp2, const float* __restrict__ Wo,
    u32* __restrict__ BF,
    const int* __restrict__ src, const int* __restrict__ dst,
    int* __restrict__ gcount, u32* __restrict__ ebuf, int E) {
    const int t = threadIdx.x;
    if (blockIdx.x < 38) {
        // ---- compose weights into MFMA B-fragment order (bf16) ----
        const int bid = blockIdx.x * 4 + (t >> 6);
        const int l = t & 63;
        const int c = l & 15;
        const int kg = l >> 4;
        float val[8];

        if (bid < 120) {
            const int ct = bid / 5, ks = bid - ct * 5;
            const int u = ct / 6, r = ct - u * 6;
            const int n = 32 * u + 16 * (r < 2 ? r : (r & 1)) + c;
#pragma unroll
            for (int j = 0; j < 8; ++j) {
                const int k = ks * 32 + kg * 8 + j;
                float v = 0.f;
                if (r < 2) {  // Q section
                    if (k < 128) {
                        float a = 0.f;
                        for (int q = 0; q < 128; ++q)
                            a = fmaf(Wq[k * 128 + q], We1[q * 128 + n], a);
                        v = a;
                    }
                } else if (r < 4) {  // K section
                    if (k < 128) {
                        float a = 0.f;
                        for (int q = 0; q < 128; ++q)
                            a = fmaf(Wk[k * 128 + q], We1[q * 128 + n], a);
                        v = a;
                    } else if (k < 131) {
                        float a = 0.f;
                        for (int q = 0; q < 128; ++q)
                            a = fmaf(Wp2[(k - 128) * 128 + q], We1[q * 128 + n], a);
                        v = a;
                    } else if (k == 131) {
                        float a = be1[n];
                        for (int q = 0; q < 128; ++q)
                            a = fmaf(bp2[q], We1[q * 128 + n], a);
                        v = a;
                    }
                } else {  // V section
                    if (k < 128) v = Wv[k * 128 + n];
                    else if (k < 131) v = Wp2[(k - 128) * 128 + n];
                    else if (k == 131) v = bp2[n];
                }
                val[j] = v;
            }
        } else {  // Wo fragments
            const int b2 = bid - 120;
            const int ct = b2 >> 2, ks = b2 & 3;
            const int n = ct * 16 + c;
#pragma unroll
            for (int j = 0; j < 8; ++j) {
                const int k = ks * 32 + kg * 8 + j;
                val[j] = Wo[k * 128 + n];
            }
        }
        u32* dp = &BF[((size_t)bid * 64 + l) * 4];
        dp[0] = pack2(val[0], val[1]);
        dp[1] = pack2(val[2], val[3]);
        dp[2] = pack2(val[4], val[5]);
        dp[3] = pack2(val[6], val[7]);
    } else {
        // ---- p1_bucket: LDS-ranked coarse bucket (dst>>9) ----
        __shared__ int hist[256];
        __shared__ int base[256];
        hist[t] = 0;
        __syncthreads();
        const int chunk = (blockIdx.x - 38) * 4096;
        int bk[16], rk[16];
        u32 pv[16];
#pragma unroll
        for (int i = 0; i < 16; ++i) {
            int idx = chunk + i * 256 + t;
            bk[i] = -1;
            if (idx < E) {
                int dd = dst[idx];
                int ss = src[idx];
                bk[i] = dd >> 9;
                pv[i] = ((u32)ss << 9) | (u32)(dd & 511);
                rk[i] = atomicAdd(&hist[bk[i]], 1);
            }
        }
        __syncthreads();
        if (hist[t]) base[t] = t * CAP + atomicAdd(&gcount[t], hist[t]);
        __syncthreads();
#pragma unroll
        for (int i = 0; i < 16; ++i) {
            if (bk[i] >= 0) ebuf[base[bk[i]] + rk[i]] = pv[i];
        }
    }
}

// ---------------------------------------------------------------------------
// scanB + We2 reorder into slot order.
// ---------------------------------------------------------------------------
__global__ __launch_bounds__(256) void scanB_we2r(
    const int* __restrict__ gcount, int* __restrict__ bucket_base,
    const float* __restrict__ We2, float* __restrict__ We2r) {
    __shared__ int s[256];
    int t = threadIdx.x;
    int orig = gcount[t];
    s[t] = orig;
    __syncthreads();
    for (int off = 1; off < 256; off <<= 1) {
        int x = (t >= off) ? s[t - off] : 0;
        __syncthreads();
        s[t] += x;
        __syncthreads();
    }
    bucket_base[t] = s[t] - orig;
    if (t < 128) {
        int col = 32 * (t >> 5) + 16 * (t & 1) + ((t & 31) >> 1);
        We2r[t] = We2[col];
    }
}

// ---------------------------------------------------------------------------
// Fused mid: p2_local (blocks 0..NR-1) || node_mfma (rest).
// GEMM epilogue: QWb bf16-pair, Vb bf16-pair, Kb8 fp8. (R7-verified)
// ---------------------------------------------------------------------------
__global__ __launch_bounds__(256) void fused_mid(
    const float* __restrict__ h, const float* __restrict__ c,
    const float* __restrict__ Wp1, const float* __restrict__ bp1,
    const u32* __restrict__ BF,
    u32* __restrict__ QWb, u32* __restrict__ Vb,
    unsigned char* __restrict__ Kb8, int N,
    const int* __restrict__ gcount, const int* __restrict__ bucket_base,
    const u32* __restrict__ ebuf, int* __restrict__ ssrc,
    int* __restrict__ offs, int E, int NR) {
    __shared__ u32 lds[64 * 96];  // 24 KB, aliased by both paths
    const int t = threadIdx.x;

    if ((int)blockIdx.x < NR) {
        // ---- p2_local: per-bucket CSR finalize ----
        int* cnt = (int*)lds;        // 512
        int* cur = cnt + 512;        // 512
        int* ts = cur + 512;         // 256
        const int r = blockIdx.x;
        const int cnt_r = gcount[r];
        const int base_r = bucket_base[r];
        cnt[t] = 0;
        cnt[t + 256] = 0;
        __syncthreads();
        const u32* eb = &ebuf[(size_t)r * CAP];
        for (int i = t; i < cnt_r; i += 256) atomicAdd(&cnt[eb[i] & 511], 1);
        __syncthreads();
        int v0 = cnt[2 * t], v1 = cnt[2 * t + 1];
        int pair = v0 + v1;
        ts[t] = pair;
        __syncthreads();
        for (int off = 1; off < 256; off <<= 1) {
            int x = (t >= off) ? ts[t - off] : 0;
            __syncthreads();
            ts[t] += x;
            __syncthreads();
        }
        int ex = ts[t] - pair;
        cur[2 * t] = ex;
        cur[2 * t + 1] = ex + v0;
        offs[r * 512 + 2 * t] = base_r + ex;
        offs[r * 512 + 2 * t + 1] = base_r + ex + v0;
        if (r == NR - 1 && t == 255) offs[NR * 512] = E;
        __syncthreads();
        for (int i = t; i < cnt_r; i += 256) {
            u32 e = eb[i];
            int p = atomicAdd(&cur[e & 511], 1);
            ssrc[base_r + p] = (int)(e >> 9);
        }
    } else {
        // ---- node_mfma: [N x 160] @ [160 x 384] bf16 MFMA GEMM ----
        u32* hs = lds;
        const int row0 = ((int)blockIdx.x - NR) * 64;

#pragma unroll
        for (int i = 0; i < 8; ++i) {
            int f = t + i * 256;
            int row = f >> 5;
            int cq = f & 31;
            float4 v = f4zero();
            if (row0 + row < N) v = *(const float4*)&h[(size_t)(row0 + row) * DD + cq * 4];
            int idx = row * 96 + ((cq * 2) ^ ((row & 7) << 2));
            uint2 p;
            p.x = pack2(v.x, v.y);
            p.y = pack2(v.z, v.w);
            *(uint2*)&hs[idx] = p;
        }
        if (t < 64) {
            int row = t;
            float u0 = 0.f, u1 = 0.f, u2 = 0.f;
            if (row0 + row < N) {
                const float* cr = &c[(size_t)(row0 + row) * 3];
                float c0 = cr[0], c1 = cr[1], c2 = cr[2];
                u0 = fmaxf(bp1[0] + c0 * Wp1[0] + c1 * Wp1[3] + c2 * Wp1[6], 0.f);
                u1 = fmaxf(bp1[1] + c0 * Wp1[1] + c1 * Wp1[4] + c2 * Wp1[7], 0.f);
                u2 = fmaxf(bp1[2] + c0 * Wp1[2] + c1 * Wp1[5] + c2 * Wp1[8], 0.f);
            }
            int swz = (row & 7) << 2;
            uint4 z0 = make_uint4(pack2(u0, u1), pack2(u2, 1.0f), 0u, 0u);
            uint4 zz = make_uint4(0u, 0u, 0u, 0u);
#pragma unroll
            for (int q = 0; q < 4; ++q) {
                int idx = row * 96 + 64 + ((q * 4) ^ swz);
                *(uint4*)&hs[idx] = (q == 0) ? z0 : zz;
            }
        }
        __syncthreads();

        const int w = t >> 6, l = t & 63;
        const int cc = l & 15, kg = l >> 4;

        f32x4 acc[4][6];
#pragma unroll
        for (int rt = 0; rt < 4; ++rt)
#pragma unroll
            for (int r = 0; r < 6; ++r) acc[rt][r] = (f32x4){0.f, 0.f, 0.f, 0.f};

#pragma unroll
        for (int ks = 0; ks < 5; ++ks) {
            bf16x8 a[4];
#pragma unroll
            for (int rt = 0; rt < 4; ++rt) {
                int row = rt * 16 + cc;
                int idx = row * 96 + ((ks * 16 + kg * 4) ^ ((row & 7) << 2));
                a[rt] = *(const bf16x8*)&hs[idx];
            }
#pragma unroll
            for (int r = 0; r < 6; ++r) {
                const bf16x8 b = *(const bf16x8*)&BF[(((size_t)(w * 6 + r) * 5 + ks) * 64 + l) * 4];
#pragma unroll
                for (int rt = 0; rt < 4; ++rt)
                    acc[rt][r] = __builtin_amdgcn_mfma_f32_16x16x32_bf16(a[rt], b, acc[rt][r], 0, 0, 0);
            }
        }

#pragma unroll
        for (int rt = 0; rt < 4; ++rt) {
#pragma unroll
            for (int j = 0; j < 4; ++j) {
                int row = row0 + rt * 16 + kg * 4 + j;
                if (row >= N) continue;
                QWb[(size_t)row * 64 + w * 16 + cc] = pack2(acc[rt][0][j], acc[rt][1][j]);
                Vb[(size_t)row * 64 + w * 16 + cc] = pack2(acc[rt][4][j], acc[rt][5][j]);
                u32 kp = __builtin_amdgcn_cvt_pk_fp8_f32(acc[rt][2][j], acc[rt][3][j], 0u, false);
                *(u16*)&Kb8[(size_t)row * 128 + w * 32 + cc * 2] = (u16)kp;
            }
        }
    }
}

// ---------------------------------------------------------------------------
// Aggregate: quarter-wave (16-lane) groups, 4 edges in flight/wave.
// fp8 K (8 B/lane) + bf16 V (16 B/lane). Software-pipelined: payload for
// iteration t+1 loads during iteration t's compute; index fetched 2 ahead.
// ---------------------------------------------------------------------------
__global__ __launch_bounds__(256) void aggregate(
    const int* __restrict__ offs, const int* __restrict__ ssrc,
    const unsigned char* __restrict__ Kb8, const u32* __restrict__ Vb,
    const u32* __restrict__ QWb, const float* __restrict__ We2r,
    const float* __restrict__ be2, u32* __restrict__ headb, int N) {
    const int node = (blockIdx.x * 256 + threadIdx.x) >> 6;
    const int lane = threadIdx.x & 63;
    if (node >= N) return;
    const int g = lane >> 4, i = lane & 15;

    const float SC = 0.08838834764831845f * 1.4426950408889634f;  // (1/sqrt128)*log2e
    const float CL = 5.0f * 1.4426950408889634f;

    uint4 Qu = *(const uint4*)&QWb[(size_t)node * 64 + 4 * i];
    float q0 = unlo(Qu.x), q1 = unhi(Qu.x), q2 = unlo(Qu.y), q3 = unhi(Qu.y);
    float q4 = unlo(Qu.z), q5 = unhi(Qu.z), q6 = unlo(Qu.w), q7 = unhi(Qu.w);
    float4 wA = *(const float4*)&We2r[8 * i];
    float4 wB = *(const float4*)&We2r[8 * i + 4];
    float b2 = be2[0];

    const int beg = offs[node], end = offs[node + 1];
    float a0 = 0.f, a1 = 0.f, a2 = 0.f, a3 = 0.f;
    float a4 = 0.f, a5 = 0.f, a6 = 0.f, a7 = 0.f;
    float zacc = 0.f;

    // pipeline prologue: index+payload for iter 0; index for iter 1
    int s0 = (beg + g < end) ? ssrc[beg + g] : 0;
    int s1 = (beg + 4 + g < end) ? ssrc[beg + 4 + g] : 0;
    uint2 kk = *(const uint2*)&Kb8[(size_t)s0 * 128 + 8 * i];
    uint4 va = *(const uint4*)&Vb[(size_t)s0 * 64 + 4 * i];

    for (int e0 = beg; e0 < end; e0 += 4) {
        const bool act = (e0 + g) < end;
        const uint2 kkc = kk;
        const uint4 vac = va;

        // prefetch: index for iter+2, payload for iter+1 (address ready)
        int en2 = e0 + 8 + g;
        int s2 = (en2 < end) ? ssrc[en2] : 0;
        kk = *(const uint2*)&Kb8[(size_t)s1 * 128 + 8 * i];
        va = *(const uint4*)&Vb[(size_t)s1 * 64 + 4 * i];
        s1 = s2;

        f32x2 f0 = __builtin_amdgcn_cvt_pk_f32_fp8(kkc.x, false);
        f32x2 f1 = __builtin_amdgcn_cvt_pk_f32_fp8(kkc.x, true);
        f32x2 f2 = __builtin_amdgcn_cvt_pk_f32_fp8(kkc.y, false);
        f32x2 f3 = __builtin_amdgcn_cvt_pk_f32_fp8(kkc.y, true);

        float p;
        p = fmaxf(f0[0] - q0, 0.f) * wA.x;
        p = fmaf(fmaxf(f0[1] - q1, 0.f), wA.y, p);
        p = fmaf(fmaxf(f1[0] - q2, 0.f), wA.z, p);
        p = fmaf(fmaxf(f1[1] - q3, 0.f), wA.w, p);
        p = fmaf(fmaxf(f2[0] - q4, 0.f), wB.x, p);
        p = fmaf(fmaxf(f2[1] - q5, 0.f), wB.y, p);
        p = fmaf(fmaxf(f3[0] - q6, 0.f), wB.z, p);
        p = fmaf(fmaxf(f3[1] - q7, 0.f), wB.w, p);
#pragma unroll
        for (int off = 1; off <= 8; off <<= 1) p += __shfl_xor(p, off);

        float targ = (p + b2) * SC;
        targ = fminf(fmaxf(targ, -CL), CL);
        float sc = act ? exp2f(targ) : 0.f;

        a0 = fmaf(unlo(vac.x), sc, a0);
        a1 = fmaf(unhi(vac.x), sc, a1);
        a2 = fmaf(unlo(vac.y), sc, a2);
        a3 = fmaf(unhi(vac.y), sc, a3);
        a4 = fmaf(unlo(vac.z), sc, a4);
        a5 = fmaf(unhi(vac.z), sc, a5);
        a6 = fmaf(unlo(vac.w), sc, a6);
        a7 = fmaf(unhi(vac.w), sc, a7);
        zacc += sc;
    }

    // cross-group combine
    a0 += __shfl_xor(a0, 16); a0 += __shfl_xor(a0, 32);
    a1 += __shfl_xor(a1, 16); a1 += __shfl_xor(a1, 32);
    a2 += __shfl_xor(a2, 16); a2 += __shfl_xor(a2, 32);
    a3 += __shfl_xor(a3, 16); a3 += __shfl_xor(a3, 32);
    a4 += __shfl_xor(a4, 16); a4 += __shfl_xor(a4, 32);
    a5 += __shfl_xor(a5, 16); a5 += __shfl_xor(a5, 32);
    a6 += __shfl_xor(a6, 16); a6 += __shfl_xor(a6, 32);
    a7 += __shfl_xor(a7, 16); a7 += __shfl_xor(a7, 32);
    zacc += __shfl_xor(zacc, 16); zacc += __shfl_xor(zacc, 32);

    if (g == 0) {
        float rz = 1.0f / zacc;
        uint4 o;
        o.x = pack2(a0 * rz, a1 * rz);
        o.y = pack2(a2 * rz, a3 * rz);
        o.z = pack2(a4 * rz, a5 * rz);
        o.w = pack2(a6 * rz, a7 * rz);
        *(uint4*)&headb[(size_t)node * 64 + 4 * i] = o;
    }
}

// ---------------------------------------------------------------------------
// out = head @ Wo + bo via MFMA (unchanged — verified).
// ---------------------------------------------------------------------------
__global__ __launch_bounds__(256) void out_mfma(
    const u32* __restrict__ headb, const u32* __restrict__ WoF,
    const float* __restrict__ bo, float* __restrict__ out, int N) {
    __shared__ u32 hs[64 * 64];

    const int row0 = blockIdx.x * 64;
    const int t = threadIdx.x;

#pragma unroll
    for (int i = 0; i < 4; ++i) {
        int f = t + i * 256;
        int row = f >> 4;
        int cq = f & 15;
        uint4 v = make_uint4(0u, 0u, 0u, 0u);
        if (row0 + row < N) v = *(const uint4*)&headb[(size_t)(row0 + row) * 64 + cq * 4];
        int m = cq >> 2;
        int cb = (cq & 3) * 4;
        int swz = (row & 7) << 2;
        uint2 A, B;
        A.x = (v.x & 0xFFFFu) | (v.y << 16);
        A.y = (v.z & 0xFFFFu) | (v.w << 16);
        B.x = (v.x >> 16) | (v.y & 0xFFFF0000u);
        B.y = (v.z >> 16) | (v.w & 0xFFFF0000u);
        int dA = 16 * m + (cb >> 1);
        *(uint2*)&hs[row * 64 + (dA ^ swz)] = A;
        *(uint2*)&hs[row * 64 + ((dA + 8) ^ swz)] = B;
    }
    __syncthreads();

    const int w = t >> 6, l = t & 63;
    const int cc = l & 15, kg = l >> 4;

    f32x4 acc[4][2];
#pragma unroll
    for (int rt = 0; rt < 4; ++rt) {
        acc[rt][0] = (f32x4){0.f, 0.f, 0.f, 0.f};
        acc[rt][1] = (f32x4){0.f, 0.f, 0.f, 0.f};
    }

#pragma unroll
    for (int ks = 0; ks < 4; ++ks) {
        bf16x8 a[4];
#pragma unroll
        for (int rt = 0; rt < 4; ++rt) {
            int row = rt * 16 + cc;
            int idx = row * 64 + ((ks * 16 + kg * 4) ^ ((row & 7) << 2));
            a[rt] = *(const bf16x8*)&hs[idx];
        }
#pragma unroll
        for (int ctl = 0; ctl < 2; ++ctl) {
            const bf16x8 b = *(const bf16x8*)&WoF[(((size_t)(2 * w + ctl) * 4 + ks) * 64 + l) * 4];
#pragma unroll
            for (int rt = 0; rt < 4; ++rt)
                acc[rt][ctl] = __builtin_amdgcn_mfma_f32_16x16x32_bf16(a[rt], b, acc[rt][ctl], 0, 0, 0);
        }
    }

#pragma unroll
    for (int ctl = 0; ctl < 2; ++ctl) {
        int col = (2 * w + ctl) * 16 + cc;
        float bias = bo[col];
#pragma unroll
        for (int rt = 0; rt < 4; ++rt) {
#pragma unroll
            for (int j = 0; j < 4; ++j) {
                int row = row0 + rt * 16 + kg * 4 + j;
                if (row >= N) continue;
                out[(size_t)row * DD + col] = acc[rt][ctl][j] + bias;
            }
        }
    }
}

// ---------------------------------------------------------------------------
extern "C" void kernel_launch(void* const* d_in, const int* in_sizes, int n_in,
                              void* d_out, int out_size, void* d_ws, size_t ws_size,
                              hipStream_t stream) {
    const float* h   = (const float*)d_in[0];
    const float* c   = (const float*)d_in[1];
    const int*   src = (const int*)d_in[2];
    const int*   dst = (const int*)d_in[3];
    const float* Wq  = (const float*)d_in[4];
    const float* Wk  = (const float*)d_in[5];
    const float* Wv  = (const float*)d_in[6];
    const float* Wp1 = (const float*)d_in[7];
    const float* bp1 = (const float*)d_in[8];
    const float* Wp2 = (const float*)d_in[9];
    const float* bp2 = (const float*)d_in[10];
    const float* We1 = (const float*)d_in[11];
    const float* be1 = (const float*)d_in[12];
    const float* We2 = (const float*)d_in[13];
    const float* be2 = (const float*)d_in[14];
    const float* Wo  = (const float*)d_in[15];
    const float* bo  = (const float*)d_in[16];

    const int N = in_sizes[0] / DD;
    const int E = in_sizes[2];
    const int NR = (N + 511) >> 9;        // 512-node buckets
    const int NB1 = (E + 4095) / 4096;    // p1 blocks
    const int NG = (N + 63) / 64;         // GEMM blocks

    u32* BF    = (u32*)d_ws;                       // 152*256
    u32* WoF   = BF + 120 * 256;
    u32* QWb   = BF + 152 * 256;                   // N*64 u32
    u32* Vb    = QWb + (size_t)N * 64;             // N*64 u32
    unsigned char* Kb8 = (unsigned char*)(Vb + (size_t)N * 64);  // N*128 B
    u32* headb = (u32*)(Kb8 + (size_t)N * 128);    // N*64 u32
    int* offs  = (int*)(headb + (size_t)N * 64);   // NR*512+1
    int* gcount = offs + ((size_t)NR * 512 + 1);   // 256
    int* bbase  = gcount + 256;                    // 256
    float* We2r = (float*)(bbase + 256);           // 128
    int* ssrc   = (int*)(We2r + 128);              // E
    u32* ebuf   = (u32*)(ssrc + E);                // 256*CAP

    hipMemsetAsync(gcount, 0, 256 * sizeof(int), stream);

    fused_pre<<<38 + NB1, 256, 0, stream>>>(Wq, Wk, Wv, We1, be1, Wp2, bp2, Wo,
                                            BF, src, dst, gcount, ebuf, E);

    scanB_we2r<<<1, 256, 0, stream>>>(gcount, bbase, We2, We2r);

    fused_mid<<<NR + NG, 256, 0, stream>>>(
        h, c, Wp1, bp1, BF, QWb, Vb, Kb8, N,
        gcount, bbase, ebuf, ssrc, offs, E, NR);

    aggregate<<<(N * 64 + 255) / 256, 256, 0, stream>>>(offs, ssrc, Kb8, Vb,
                                                        QWb, We2r, be2, headb, N);

    out_mfma<<<NG, 256, 0, stream>>>(headb, WoF, bo, (float*)d_out, N);
}

// Round 11
// 211.233 us; speedup vs baseline: 1.1198x; 1.0069x over previous
//
#include <hip/hip_runtime.h>
#include <math.h>

#define DD 128
#define CAP 10240
typedef unsigned int u32;
typedef unsigned short u16;
typedef __attribute__((ext_vector_type(8))) short bf16x8;
typedef __attribute__((ext_vector_type(4))) float f32x4;
typedef __attribute__((ext_vector_type(2))) float f32x2;

__device__ __forceinline__ float4 f4zero() { return make_float4(0.f, 0.f, 0.f, 0.f); }
// round-to-nearest-even f32 -> bf16 (low 16 bits)
__device__ __forceinline__ u32 bf16rne(float f) {
    u32 u = __float_as_uint(f);
    u += 0x7FFFu + ((u >> 16) & 1u);
    return u >> 16;
}
__device__ __forceinline__ u32 pack2(float lo, float hi) {
    return bf16rne(lo) | (bf16rne(hi) << 16);
}
__device__ __forceinline__ float unlo(u32 u) { return __uint_as_float(u << 16); }
__device__ __forceinline__ float unhi(u32 u) { return __uint_as_float(u & 0xFFFF0000u); }

// ---------------------------------------------------------------------------
// Fused pre: compose_frags (blocks 0..37, 4 sub-bids each) || p1_bucket.
// (verified)
// ---------------------------------------------------------------------------
__global__ __launch_bounds__(256) void fused_pre(
    const float* __restrict__ Wq, const float* __restrict__ Wk,
    const float* __restrict__ Wv, const float* __restrict__ We1,
    const float* __restrict__ be1, const float* __restrict__ Wp2,
    const float* __restrict__ bp2, const float* __restrict__ Wo,
    u32* __restrict__ BF,
    const int* __restrict__ src, const int* __restrict__ dst,
    int* __restrict__ gcount, u32* __restrict__ ebuf, int E) {
    const int t = threadIdx.x;
    if (blockIdx.x < 38) {
        // ---- compose weights into MFMA B-fragment order (bf16) ----
        const int bid = blockIdx.x * 4 + (t >> 6);
        const int l = t & 63;
        const int c = l & 15;
        const int kg = l >> 4;
        float val[8];

        if (bid < 120) {
            const int ct = bid / 5, ks = bid - ct * 5;
            const int u = ct / 6, r = ct - u * 6;
            const int n = 32 * u + 16 * (r < 2 ? r : (r & 1)) + c;
#pragma unroll
            for (int j = 0; j < 8; ++j) {
                const int k = ks * 32 + kg * 8 + j;
                float v = 0.f;
                if (r < 2) {  // Q section
                    if (k < 128) {
                        float a = 0.f;
                        for (int q = 0; q < 128; ++q)
                            a = fmaf(Wq[k * 128 + q], We1[q * 128 + n], a);
                        v = a;
                    }
                } else if (r < 4) {  // K section
                    if (k < 128) {
                        float a = 0.f;
                        for (int q = 0; q < 128; ++q)
                            a = fmaf(Wk[k * 128 + q], We1[q * 128 + n], a);
                        v = a;
                    } else if (k < 131) {
                        float a = 0.f;
                        for (int q = 0; q < 128; ++q)
                            a = fmaf(Wp2[(k - 128) * 128 + q], We1[q * 128 + n], a);
                        v = a;
                    } else if (k == 131) {
                        float a = be1[n];
                        for (int q = 0; q < 128; ++q)
                            a = fmaf(bp2[q], We1[q * 128 + n], a);
                        v = a;
                    }
                } else {  // V section
                    if (k < 128) v = Wv[k * 128 + n];
                    else if (k < 131) v = Wp2[(k - 128) * 128 + n];
                    else if (k == 131) v = bp2[n];
                }
                val[j] = v;
            }
        } else {  // Wo fragments
            const int b2 = bid - 120;
            const int ct = b2 >> 2, ks = b2 & 3;
            const int n = ct * 16 + c;
#pragma unroll
            for (int j = 0; j < 8; ++j) {
                const int k = ks * 32 + kg * 8 + j;
                val[j] = Wo[k * 128 + n];
            }
        }
        u32* dp = &BF[((size_t)bid * 64 + l) * 4];
        dp[0] = pack2(val[0], val[1]);
        dp[1] = pack2(val[2], val[3]);
        dp[2] = pack2(val[4], val[5]);
        dp[3] = pack2(val[6], val[7]);
    } else {
        // ---- p1_bucket: LDS-ranked coarse bucket (dst>>9) ----
        __shared__ int hist[256];
        __shared__ int base[256];
        hist[t] = 0;
        __syncthreads();
        const int chunk = (blockIdx.x - 38) * 4096;
        int bk[16], rk[16];
        u32 pv[16];
#pragma unroll
        for (int i = 0; i < 16; ++i) {
            int idx = chunk + i * 256 + t;
            bk[i] = -1;
            if (idx < E) {
                int dd = dst[idx];
                int ss = src[idx];
                bk[i] = dd >> 9;
                pv[i] = ((u32)ss << 9) | (u32)(dd & 511);
                rk[i] = atomicAdd(&hist[bk[i]], 1);
            }
        }
        __syncthreads();
        if (hist[t]) base[t] = t * CAP + atomicAdd(&gcount[t], hist[t]);
        __syncthreads();
#pragma unroll
        for (int i = 0; i < 16; ++i) {
            if (bk[i] >= 0) ebuf[base[bk[i]] + rk[i]] = pv[i];
        }
    }
}

// ---------------------------------------------------------------------------
// scanB + We2 reorder into slot order.
// ---------------------------------------------------------------------------
__global__ __launch_bounds__(256) void scanB_we2r(
    const int* __restrict__ gcount, int* __restrict__ bucket_base,
    const float* __restrict__ We2, float* __restrict__ We2r) {
    __shared__ int s[256];
    int t = threadIdx.x;
    int orig = gcount[t];
    s[t] = orig;
    __syncthreads();
    for (int off = 1; off < 256; off <<= 1) {
        int x = (t >= off) ? s[t - off] : 0;
        __syncthreads();
        s[t] += x;
        __syncthreads();
    }
    bucket_base[t] = s[t] - orig;
    if (t < 128) {
        int col = 32 * (t >> 5) + 16 * (t & 1) + ((t & 31) >> 1);
        We2r[t] = We2[col];
    }
}

// ---------------------------------------------------------------------------
// Fused mid: p2_local (blocks 0..NR-1) || node_mfma (rest).
// GEMM epilogue: QWb bf16-pair; KV interleaved row (384 B/node:
//   bytes [0,128) K fp8 slot-ordered, bytes [128,384) V bf16 pairs).
// ---------------------------------------------------------------------------
__global__ __launch_bounds__(256) void fused_mid(
    const float* __restrict__ h, const float* __restrict__ c,
    const float* __restrict__ Wp1, const float* __restrict__ bp1,
    const u32* __restrict__ BF,
    u32* __restrict__ QWb, unsigned char* __restrict__ KV, int N,
    const int* __restrict__ gcount, const int* __restrict__ bucket_base,
    const u32* __restrict__ ebuf, int* __restrict__ ssrc,
    int* __restrict__ offs, int E, int NR) {
    __shared__ u32 lds[64 * 96];  // 24 KB, aliased by both paths
    const int t = threadIdx.x;

    if ((int)blockIdx.x < NR) {
        // ---- p2_local: per-bucket CSR finalize ----
        int* cnt = (int*)lds;        // 512
        int* cur = cnt + 512;        // 512
        int* ts = cur + 512;         // 256
        const int r = blockIdx.x;
        const int cnt_r = gcount[r];
        const int base_r = bucket_base[r];
        cnt[t] = 0;
        cnt[t + 256] = 0;
        __syncthreads();
        const u32* eb = &ebuf[(size_t)r * CAP];
        for (int i = t; i < cnt_r; i += 256) atomicAdd(&cnt[eb[i] & 511], 1);
        __syncthreads();
        int v0 = cnt[2 * t], v1 = cnt[2 * t + 1];
        int pair = v0 + v1;
        ts[t] = pair;
        __syncthreads();
        for (int off = 1; off < 256; off <<= 1) {
            int x = (t >= off) ? ts[t - off] : 0;
            __syncthreads();
            ts[t] += x;
            __syncthreads();
        }
        int ex = ts[t] - pair;
        cur[2 * t] = ex;
        cur[2 * t + 1] = ex + v0;
        offs[r * 512 + 2 * t] = base_r + ex;
        offs[r * 512 + 2 * t + 1] = base_r + ex + v0;
        if (r == NR - 1 && t == 255) offs[NR * 512] = E;
        __syncthreads();
        for (int i = t; i < cnt_r; i += 256) {
            u32 e = eb[i];
            int p = atomicAdd(&cur[e & 511], 1);
            ssrc[base_r + p] = (int)(e >> 9);
        }
    } else {
        // ---- node_mfma: [N x 160] @ [160 x 384] bf16 MFMA GEMM ----
        u32* hs = lds;
        const int row0 = ((int)blockIdx.x - NR) * 64;

#pragma unroll
        for (int i = 0; i < 8; ++i) {
            int f = t + i * 256;
            int row = f >> 5;
            int cq = f & 31;
            float4 v = f4zero();
            if (row0 + row < N) v = *(const float4*)&h[(size_t)(row0 + row) * DD + cq * 4];
            int idx = row * 96 + ((cq * 2) ^ ((row & 7) << 2));
            uint2 p;
            p.x = pack2(v.x, v.y);
            p.y = pack2(v.z, v.w);
            *(uint2*)&hs[idx] = p;
        }
        if (t < 64) {
            int row = t;
            float u0 = 0.f, u1 = 0.f, u2 = 0.f;
            if (row0 + row < N) {
                const float* cr = &c[(size_t)(row0 + row) * 3];
                float c0 = cr[0], c1 = cr[1], c2 = cr[2];
                u0 = fmaxf(bp1[0] + c0 * Wp1[0] + c1 * Wp1[3] + c2 * Wp1[6], 0.f);
                u1 = fmaxf(bp1[1] + c0 * Wp1[1] + c1 * Wp1[4] + c2 * Wp1[7], 0.f);
                u2 = fmaxf(bp1[2] + c0 * Wp1[2] + c1 * Wp1[5] + c2 * Wp1[8], 0.f);
            }
            int swz = (row & 7) << 2;
            uint4 z0 = make_uint4(pack2(u0, u1), pack2(u2, 1.0f), 0u, 0u);
            uint4 zz = make_uint4(0u, 0u, 0u, 0u);
#pragma unroll
            for (int q = 0; q < 4; ++q) {
                int idx = row * 96 + 64 + ((q * 4) ^ swz);
                *(uint4*)&hs[idx] = (q == 0) ? z0 : zz;
            }
        }
        __syncthreads();

        const int w = t >> 6, l = t & 63;
        const int cc = l & 15, kg = l >> 4;

        f32x4 acc[4][6];
#pragma unroll
        for (int rt = 0; rt < 4; ++rt)
#pragma unroll
            for (int r = 0; r < 6; ++r) acc[rt][r] = (f32x4){0.f, 0.f, 0.f, 0.f};

#pragma unroll
        for (int ks = 0; ks < 5; ++ks) {
            bf16x8 a[4];
#pragma unroll
            for (int rt = 0; rt < 4; ++rt) {
                int row = rt * 16 + cc;
                int idx = row * 96 + ((ks * 16 + kg * 4) ^ ((row & 7) << 2));
                a[rt] = *(const bf16x8*)&hs[idx];
            }
#pragma unroll
            for (int r = 0; r < 6; ++r) {
                const bf16x8 b = *(const bf16x8*)&BF[(((size_t)(w * 6 + r) * 5 + ks) * 64 + l) * 4];
#pragma unroll
                for (int rt = 0; rt < 4; ++rt)
                    acc[rt][r] = __builtin_amdgcn_mfma_f32_16x16x32_bf16(a[rt], b, acc[rt][r], 0, 0, 0);
            }
        }

#pragma unroll
        for (int rt = 0; rt < 4; ++rt) {
#pragma unroll
            for (int j = 0; j < 4; ++j) {
                int row = row0 + rt * 16 + kg * 4 + j;
                if (row >= N) continue;
                QWb[(size_t)row * 64 + w * 16 + cc] = pack2(acc[rt][0][j], acc[rt][1][j]);
                unsigned char* kvrow = &KV[(size_t)row * 384];
                u32 kp = __builtin_amdgcn_cvt_pk_fp8_f32(acc[rt][2][j], acc[rt][3][j], 0u, false);
                *(u16*)&kvrow[w * 32 + cc * 2] = (u16)kp;
                *(u32*)&kvrow[128 + 4 * (w * 16 + cc)] = pack2(acc[rt][4][j], acc[rt][5][j]);
            }
        }
    }
}

// ---------------------------------------------------------------------------
// Aggregate: quarter-wave (16-lane) groups, 4 edges in flight/wave.
// Interleaved KV row (one address calc); packed f32x2 math on score and
// accumulate chains (v_pk_fma_f32 path); index-only prefetch.
// ---------------------------------------------------------------------------
__global__ __launch_bounds__(256) void aggregate(
    const int* __restrict__ offs, const int* __restrict__ ssrc,
    const unsigned char* __restrict__ KV, const u32* __restrict__ QWb,
    const float* __restrict__ We2r, const float* __restrict__ be2,
    u32* __restrict__ headb, int N) {
    const int node = (blockIdx.x * 256 + threadIdx.x) >> 6;
    const int lane = threadIdx.x & 63;
    if (node >= N) return;
    const int g = lane >> 4, i = lane & 15;

    const float SC = 0.08838834764831845f * 1.4426950408889634f;  // (1/sqrt128)*log2e
    const float CL = 5.0f * 1.4426950408889634f;

    uint4 Qu = *(const uint4*)&QWb[(size_t)node * 64 + 4 * i];
    f32x2 q01 = {unlo(Qu.x), unhi(Qu.x)};
    f32x2 q23 = {unlo(Qu.y), unhi(Qu.y)};
    f32x2 q45 = {unlo(Qu.z), unhi(Qu.z)};
    f32x2 q67 = {unlo(Qu.w), unhi(Qu.w)};
    f32x2 w01 = *(const f32x2*)&We2r[8 * i];
    f32x2 w23 = *(const f32x2*)&We2r[8 * i + 2];
    f32x2 w45 = *(const f32x2*)&We2r[8 * i + 4];
    f32x2 w67 = *(const f32x2*)&We2r[8 * i + 6];
    const float B2SC = be2[0] * SC;
    const f32x2 zero2 = {0.f, 0.f};

    const int beg = offs[node], end = offs[node + 1];
    f32x2 acc01 = zero2, acc23 = zero2, acc45 = zero2, acc67 = zero2;
    float zacc = 0.f;

    int e = beg + g;
    int s = (e < end) ? ssrc[e] : 0;
    for (int e0 = beg; e0 < end; e0 += 4) {
        const bool act = (e0 + g) < end;
        const unsigned char* row = &KV[(size_t)s * 384];
        uint2 kk = *(const uint2*)&row[8 * i];
        uint4 vv = *(const uint4*)&row[128 + 16 * i];
        int en = e0 + 4 + g;
        s = (en < end) ? ssrc[en] : 0;  // prefetch next group edge index

        f32x2 d, p2;
        d = __builtin_amdgcn_cvt_pk_f32_fp8(kk.x, false) - q01;
        d = __builtin_elementwise_max(d, zero2);
        p2 = d * w01;
        d = __builtin_amdgcn_cvt_pk_f32_fp8(kk.x, true) - q23;
        d = __builtin_elementwise_max(d, zero2);
        p2 += d * w23;
        d = __builtin_amdgcn_cvt_pk_f32_fp8(kk.y, false) - q45;
        d = __builtin_elementwise_max(d, zero2);
        p2 += d * w45;
        d = __builtin_amdgcn_cvt_pk_f32_fp8(kk.y, true) - q67;
        d = __builtin_elementwise_max(d, zero2);
        p2 += d * w67;
        float p = p2[0] + p2[1];
#pragma unroll
        for (int off = 1; off <= 8; off <<= 1) p += __shfl_xor(p, off);

        float targ = fmaf(p, SC, B2SC);
        targ = fminf(fmaxf(targ, -CL), CL);
        float sc = act ? exp2f(targ) : 0.f;
        f32x2 sc2 = {sc, sc};

        f32x2 v;
        v = (f32x2){unlo(vv.x), unhi(vv.x)}; acc01 += v * sc2;
        v = (f32x2){unlo(vv.y), unhi(vv.y)}; acc23 += v * sc2;
        v = (f32x2){unlo(vv.z), unhi(vv.z)}; acc45 += v * sc2;
        v = (f32x2){unlo(vv.w), unhi(vv.w)}; acc67 += v * sc2;
        zacc += sc;
    }

    float a0 = acc01[0], a1 = acc01[1], a2 = acc23[0], a3 = acc23[1];
    float a4 = acc45[0], a5 = acc45[1], a6 = acc67[0], a7 = acc67[1];

    // cross-group combine
    a0 += __shfl_xor(a0, 16); a0 += __shfl_xor(a0, 32);
    a1 += __shfl_xor(a1, 16); a1 += __shfl_xor(a1, 32);
    a2 += __shfl_xor(a2, 16); a2 += __shfl_xor(a2, 32);
    a3 += __shfl_xor(a3, 16); a3 += __shfl_xor(a3, 32);
    a4 += __shfl_xor(a4, 16); a4 += __shfl_xor(a4, 32);
    a5 += __shfl_xor(a5, 16); a5 += __shfl_xor(a5, 32);
    a6 += __shfl_xor(a6, 16); a6 += __shfl_xor(a6, 32);
    a7 += __shfl_xor(a7, 16); a7 += __shfl_xor(a7, 32);
    zacc += __shfl_xor(zacc, 16); zacc += __shfl_xor(zacc, 32);

    if (g == 0) {
        float rz = 1.0f / zacc;
        uint4 o;
        o.x = pack2(a0 * rz, a1 * rz);
        o.y = pack2(a2 * rz, a3 * rz);
        o.z = pack2(a4 * rz, a5 * rz);
        o.w = pack2(a6 * rz, a7 * rz);
        *(uint4*)&headb[(size_t)node * 64 + 4 * i] = o;
    }
}

// ---------------------------------------------------------------------------
// out = head @ Wo + bo via MFMA (unchanged — verified).
// ---------------------------------------------------------------------------
__global__ __launch_bounds__(256) void out_mfma(
    const u32* __restrict__ headb, const u32* __restrict__ WoF,
    const float* __restrict__ bo, float* __restrict__ out, int N) {
    __shared__ u32 hs[64 * 64];

    const int row0 = blockIdx.x * 64;
    const int t = threadIdx.x;

#pragma unroll
    for (int i = 0; i < 4; ++i) {
        int f = t + i * 256;
        int row = f >> 4;
        int cq = f & 15;
        uint4 v = make_uint4(0u, 0u, 0u, 0u);
        if (row0 + row < N) v = *(const uint4*)&headb[(size_t)(row0 + row) * 64 + cq * 4];
        int m = cq >> 2;
        int cb = (cq & 3) * 4;
        int swz = (row & 7) << 2;
        uint2 A, B;
        A.x = (v.x & 0xFFFFu) | (v.y << 16);
        A.y = (v.z & 0xFFFFu) | (v.w << 16);
        B.x = (v.x >> 16) | (v.y & 0xFFFF0000u);
        B.y = (v.z >> 16) | (v.w & 0xFFFF0000u);
        int dA = 16 * m + (cb >> 1);
        *(uint2*)&hs[row * 64 + (dA ^ swz)] = A;
        *(uint2*)&hs[row * 64 + ((dA + 8) ^ swz)] = B;
    }
    __syncthreads();

    const int w = t >> 6, l = t & 63;
    const int cc = l & 15, kg = l >> 4;

    f32x4 acc[4][2];
#pragma unroll
    for (int rt = 0; rt < 4; ++rt) {
        acc[rt][0] = (f32x4){0.f, 0.f, 0.f, 0.f};
        acc[rt][1] = (f32x4){0.f, 0.f, 0.f, 0.f};
    }

#pragma unroll
    for (int ks = 0; ks < 4; ++ks) {
        bf16x8 a[4];
#pragma unroll
        for (int rt = 0; rt < 4; ++rt) {
            int row = rt * 16 + cc;
            int idx = row * 64 + ((ks * 16 + kg * 4) ^ ((row & 7) << 2));
            a[rt] = *(const bf16x8*)&hs[idx];
        }
#pragma unroll
        for (int ctl = 0; ctl < 2; ++ctl) {
            const bf16x8 b = *(const bf16x8*)&WoF[(((size_t)(2 * w + ctl) * 4 + ks) * 64 + l) * 4];
#pragma unroll
            for (int rt = 0; rt < 4; ++rt)
                acc[rt][ctl] = __builtin_amdgcn_mfma_f32_16x16x32_bf16(a[rt], b, acc[rt][ctl], 0, 0, 0);
        }
    }

#pragma unroll
    for (int ctl = 0; ctl < 2; ++ctl) {
        int col = (2 * w + ctl) * 16 + cc;
        float bias = bo[col];
#pragma unroll
        for (int rt = 0; rt < 4; ++rt) {
#pragma unroll
            for (int j = 0; j < 4; ++j) {
                int row = row0 + rt * 16 + kg * 4 + j;
                if (row >= N) continue;
                out[(size_t)row * DD + col] = acc[rt][ctl][j] + bias;
            }
        }
    }
}

// ---------------------------------------------------------------------------
extern "C" void kernel_launch(void* const* d_in, const int* in_sizes, int n_in,
                              void* d_out, int out_size, void* d_ws, size_t ws_size,
                              hipStream_t stream) {
    const float* h   = (const float*)d_in[0];
    const float* c   = (const float*)d_in[1];
    const int*   src = (const int*)d_in[2];
    const int*   dst = (const int*)d_in[3];
    const float* Wq  = (const float*)d_in[4];
    const float* Wk  = (const float*)d_in[5];
    const float* Wv  = (const float*)d_in[6];
    const float* Wp1 = (const float*)d_in[7];
    const float* bp1 = (const float*)d_in[8];
    const float* Wp2 = (const float*)d_in[9];
    const float* bp2 = (const float*)d_in[10];
    const float* We1 = (const float*)d_in[11];
    const float* be1 = (const float*)d_in[12];
    const float* We2 = (const float*)d_in[13];
    const float* be2 = (const float*)d_in[14];
    const float* Wo  = (const float*)d_in[15];
    const float* bo  = (const float*)d_in[16];

    const int N = in_sizes[0] / DD;
    const int E = in_sizes[2];
    const int NR = (N + 511) >> 9;        // 512-node buckets
    const int NB1 = (E + 4095) / 4096;    // p1 blocks
    const int NG = (N + 63) / 64;         // GEMM blocks

    u32* BF    = (u32*)d_ws;                       // 152*256
    u32* WoF   = BF + 120 * 256;
    u32* QWb   = BF + 152 * 256;                   // N*64 u32
    unsigned char* KV = (unsigned char*)(QWb + (size_t)N * 64);  // N*384 B
    u32* headb = (u32*)(KV + (size_t)N * 384);     // N*64 u32
    int* offs  = (int*)(headb + (size_t)N * 64);   // NR*512+1
    int* gcount = offs + ((size_t)NR * 512 + 1);   // 256
    int* bbase  = gcount + 256;                    // 256
    float* We2r = (float*)(bbase + 256);           // 128
    int* ssrc   = (int*)(We2r + 128);              // E
    u32* ebuf   = (u32*)(ssrc + E);                // 256*CAP

    hipMemsetAsync(gcount, 0, 256 * sizeof(int), stream);

    fused_pre<<<38 + NB1, 256, 0, stream>>>(Wq, Wk, Wv, We1, be1, Wp2, bp2, Wo,
                                            BF, src, dst, gcount, ebuf, E);

    scanB_we2r<<<1, 256, 0, stream>>>(gcount, bbase, We2, We2r);

    fused_mid<<<NR + NG, 256, 0, stream>>>(
        h, c, Wp1, bp1, BF, QWb, KV, N,
        gcount, bbase, ebuf, ssrc, offs, E, NR);

    aggregate<<<(N * 64 + 255) / 256, 256, 0, stream>>>(offs, ssrc, KV, QWb,
                                                        We2r, be2, headb, N);

    out_mfma<<<NG, 256, 0, stream>>>(headb, WoF, bo, (float*)d_out, N);
}

// Round 12
// 195.769 us; speedup vs baseline: 1.2082x; 1.0790x over previous
//
#include <hip/hip_runtime.h>
#include <math.h>

#define DD 128
#define CAP 10240
typedef unsigned int u32;
typedef unsigned short u16;
typedef __attribute__((ext_vector_type(8))) short bf16x8;
typedef __attribute__((ext_vector_type(4))) float f32x4;
typedef __attribute__((ext_vector_type(2))) float f32x2;

__device__ __forceinline__ float4 f4zero() { return make_float4(0.f, 0.f, 0.f, 0.f); }
// round-to-nearest-even f32 -> bf16 (low 16 bits)
__device__ __forceinline__ u32 bf16rne(float f) {
    u32 u = __float_as_uint(f);
    u += 0x7FFFu + ((u >> 16) & 1u);
    return u >> 16;
}
__device__ __forceinline__ u32 pack2(float lo, float hi) {
    return bf16rne(lo) | (bf16rne(hi) << 16);
}
__device__ __forceinline__ float unlo(u32 u) { return __uint_as_float(u << 16); }
__device__ __forceinline__ float unhi(u32 u) { return __uint_as_float(u & 0xFFFF0000u); }

// ---------------------------------------------------------------------------
// Fused pre: compose_frags (blocks 0..29, 4 sub-bids each = 120) || p1_bucket.
// B' sections: Q = Wq@We1 ; K = Wk@We1 / Wp2@We1 / bp2@We1+be1 ;
//              V = Wv@Wo / Wp2@Wo / bp2@Wo   (VPo folding — out_mfma removed)
// ---------------------------------------------------------------------------
__global__ __launch_bounds__(256) void fused_pre(
    const float* __restrict__ Wq, const float* __restrict__ Wk,
    const float* __restrict__ Wv, const float* __restrict__ We1,
    const float* __restrict__ be1, const float* __restrict__ Wp2,
    const float* __restrict__ bp2, const float* __restrict__ Wo,
    u32* __restrict__ BF,
    const int* __restrict__ src, const int* __restrict__ dst,
    int* __restrict__ gcount, u32* __restrict__ ebuf, int E) {
    const int t = threadIdx.x;
    if (blockIdx.x < 30) {
        // ---- compose weights into MFMA B-fragment order (bf16) ----
        const int bid = blockIdx.x * 4 + (t >> 6);  // 0..119
        const int l = t & 63;
        const int c = l & 15;
        const int kg = l >> 4;
        float val[8];

        const int ct = bid / 5, ks = bid - ct * 5;
        const int u = ct / 6, r = ct - u * 6;
        const int n = 32 * u + 16 * (r < 2 ? r : (r & 1)) + c;
#pragma unroll
        for (int j = 0; j < 8; ++j) {
            const int k = ks * 32 + kg * 8 + j;
            float v = 0.f;
            if (r < 2) {  // Q section
                if (k < 128) {
                    float a = 0.f;
                    for (int q = 0; q < 128; ++q)
                        a = fmaf(Wq[k * 128 + q], We1[q * 128 + n], a);
                    v = a;
                }
            } else if (r < 4) {  // K section
                if (k < 128) {
                    float a = 0.f;
                    for (int q = 0; q < 128; ++q)
                        a = fmaf(Wk[k * 128 + q], We1[q * 128 + n], a);
                    v = a;
                } else if (k < 131) {
                    float a = 0.f;
                    for (int q = 0; q < 128; ++q)
                        a = fmaf(Wp2[(k - 128) * 128 + q], We1[q * 128 + n], a);
                    v = a;
                } else if (k == 131) {
                    float a = be1[n];
                    for (int q = 0; q < 128; ++q)
                        a = fmaf(bp2[q], We1[q * 128 + n], a);
                    v = a;
                }
            } else {  // V section -> VPo rows (folded with Wo)
                if (k < 128) {
                    float a = 0.f;
                    for (int q = 0; q < 128; ++q)
                        a = fmaf(Wv[k * 128 + q], Wo[q * 128 + n], a);
                    v = a;
                } else if (k < 131) {
                    float a = 0.f;
                    for (int q = 0; q < 128; ++q)
                        a = fmaf(Wp2[(k - 128) * 128 + q], Wo[q * 128 + n], a);
                    v = a;
                } else if (k == 131) {
                    float a = 0.f;
                    for (int q = 0; q < 128; ++q)
                        a = fmaf(bp2[q], Wo[q * 128 + n], a);
                    v = a;
                }
            }
            val[j] = v;
        }
        u32* dp = &BF[((size_t)bid * 64 + l) * 4];
        dp[0] = pack2(val[0], val[1]);
        dp[1] = pack2(val[2], val[3]);
        dp[2] = pack2(val[4], val[5]);
        dp[3] = pack2(val[6], val[7]);
    } else {
        // ---- p1_bucket: LDS-ranked coarse bucket (dst>>9) ----
        __shared__ int hist[256];
        __shared__ int base[256];
        hist[t] = 0;
        __syncthreads();
        const int chunk = (blockIdx.x - 30) * 4096;
        int bk[16], rk[16];
        u32 pv[16];
#pragma unroll
        for (int i = 0; i < 16; ++i) {
            int idx = chunk + i * 256 + t;
            bk[i] = -1;
            if (idx < E) {
                int dd = dst[idx];
                int ss = src[idx];
                bk[i] = dd >> 9;
                pv[i] = ((u32)ss << 9) | (u32)(dd & 511);
                rk[i] = atomicAdd(&hist[bk[i]], 1);
            }
        }
        __syncthreads();
        if (hist[t]) base[t] = t * CAP + atomicAdd(&gcount[t], hist[t]);
        __syncthreads();
#pragma unroll
        for (int i = 0; i < 16; ++i) {
            if (bk[i] >= 0) ebuf[base[bk[i]] + rk[i]] = pv[i];
        }
    }
}

// ---------------------------------------------------------------------------
// scanB + We2 reorder into slot order.
// ---------------------------------------------------------------------------
__global__ __launch_bounds__(256) void scanB_we2r(
    const int* __restrict__ gcount, int* __restrict__ bucket_base,
    const float* __restrict__ We2, float* __restrict__ We2r) {
    __shared__ int s[256];
    int t = threadIdx.x;
    int orig = gcount[t];
    s[t] = orig;
    __syncthreads();
    for (int off = 1; off < 256; off <<= 1) {
        int x = (t >= off) ? s[t - off] : 0;
        __syncthreads();
        s[t] += x;
        __syncthreads();
    }
    bucket_base[t] = s[t] - orig;
    if (t < 128) {
        int col = 32 * (t >> 5) + 16 * (t & 1) + ((t & 31) >> 1);
        We2r[t] = We2[col];
    }
}

// ---------------------------------------------------------------------------
// Fused mid: p2_local (blocks 0..NR-1) || node_mfma (rest).
// GEMM epilogue: QWb bf16-pair; KV interleaved row (384 B/node:
//   bytes [0,128) K fp8 slot-ordered, bytes [128,384) VPo bf16 pairs).
// ---------------------------------------------------------------------------
__global__ __launch_bounds__(256) void fused_mid(
    const float* __restrict__ h, const float* __restrict__ c,
    const float* __restrict__ Wp1, const float* __restrict__ bp1,
    const u32* __restrict__ BF,
    u32* __restrict__ QWb, unsigned char* __restrict__ KV, int N,
    const int* __restrict__ gcount, const int* __restrict__ bucket_base,
    const u32* __restrict__ ebuf, int* __restrict__ ssrc,
    int* __restrict__ offs, int E, int NR) {
    __shared__ u32 lds[64 * 96];  // 24 KB, aliased by both paths
    const int t = threadIdx.x;

    if ((int)blockIdx.x < NR) {
        // ---- p2_local: per-bucket CSR finalize ----
        int* cnt = (int*)lds;        // 512
        int* cur = cnt + 512;        // 512
        int* ts = cur + 512;         // 256
        const int r = blockIdx.x;
        const int cnt_r = gcount[r];
        const int base_r = bucket_base[r];
        cnt[t] = 0;
        cnt[t + 256] = 0;
        __syncthreads();
        const u32* eb = &ebuf[(size_t)r * CAP];
        for (int i = t; i < cnt_r; i += 256) atomicAdd(&cnt[eb[i] & 511], 1);
        __syncthreads();
        int v0 = cnt[2 * t], v1 = cnt[2 * t + 1];
        int pair = v0 + v1;
        ts[t] = pair;
        __syncthreads();
        for (int off = 1; off < 256; off <<= 1) {
            int x = (t >= off) ? ts[t - off] : 0;
            __syncthreads();
            ts[t] += x;
            __syncthreads();
        }
        int ex = ts[t] - pair;
        cur[2 * t] = ex;
        cur[2 * t + 1] = ex + v0;
        offs[r * 512 + 2 * t] = base_r + ex;
        offs[r * 512 + 2 * t + 1] = base_r + ex + v0;
        if (r == NR - 1 && t == 255) offs[NR * 512] = E;
        __syncthreads();
        for (int i = t; i < cnt_r; i += 256) {
            u32 e = eb[i];
            int p = atomicAdd(&cur[e & 511], 1);
            ssrc[base_r + p] = (int)(e >> 9);
        }
    } else {
        // ---- node_mfma: [N x 160] @ [160 x 384] bf16 MFMA GEMM ----
        u32* hs = lds;
        const int row0 = ((int)blockIdx.x - NR) * 64;

#pragma unroll
        for (int i = 0; i < 8; ++i) {
            int f = t + i * 256;
            int row = f >> 5;
            int cq = f & 31;
            float4 v = f4zero();
            if (row0 + row < N) v = *(const float4*)&h[(size_t)(row0 + row) * DD + cq * 4];
            int idx = row * 96 + ((cq * 2) ^ ((row & 7) << 2));
            uint2 p;
            p.x = pack2(v.x, v.y);
            p.y = pack2(v.z, v.w);
            *(uint2*)&hs[idx] = p;
        }
        if (t < 64) {
            int row = t;
            float u0 = 0.f, u1 = 0.f, u2 = 0.f;
            if (row0 + row < N) {
                const float* cr = &c[(size_t)(row0 + row) * 3];
                float c0 = cr[0], c1 = cr[1], c2 = cr[2];
                u0 = fmaxf(bp1[0] + c0 * Wp1[0] + c1 * Wp1[3] + c2 * Wp1[6], 0.f);
                u1 = fmaxf(bp1[1] + c0 * Wp1[1] + c1 * Wp1[4] + c2 * Wp1[7], 0.f);
                u2 = fmaxf(bp1[2] + c0 * Wp1[2] + c1 * Wp1[5] + c2 * Wp1[8], 0.f);
            }
            int swz = (row & 7) << 2;
            uint4 z0 = make_uint4(pack2(u0, u1), pack2(u2, 1.0f), 0u, 0u);
            uint4 zz = make_uint4(0u, 0u, 0u, 0u);
#pragma unroll
            for (int q = 0; q < 4; ++q) {
                int idx = row * 96 + 64 + ((q * 4) ^ swz);
                *(uint4*)&hs[idx] = (q == 0) ? z0 : zz;
            }
        }
        __syncthreads();

        const int w = t >> 6, l = t & 63;
        const int cc = l & 15, kg = l >> 4;

        f32x4 acc[4][6];
#pragma unroll
        for (int rt = 0; rt < 4; ++rt)
#pragma unroll
            for (int r = 0; r < 6; ++r) acc[rt][r] = (f32x4){0.f, 0.f, 0.f, 0.f};

#pragma unroll
        for (int ks = 0; ks < 5; ++ks) {
            bf16x8 a[4];
#pragma unroll
            for (int rt = 0; rt < 4; ++rt) {
                int row = rt * 16 + cc;
                int idx = row * 96 + ((ks * 16 + kg * 4) ^ ((row & 7) << 2));
                a[rt] = *(const bf16x8*)&hs[idx];
            }
#pragma unroll
            for (int r = 0; r < 6; ++r) {
                const bf16x8 b = *(const bf16x8*)&BF[(((size_t)(w * 6 + r) * 5 + ks) * 64 + l) * 4];
#pragma unroll
                for (int rt = 0; rt < 4; ++rt)
                    acc[rt][r] = __builtin_amdgcn_mfma_f32_16x16x32_bf16(a[rt], b, acc[rt][r], 0, 0, 0);
            }
        }

#pragma unroll
        for (int rt = 0; rt < 4; ++rt) {
#pragma unroll
            for (int j = 0; j < 4; ++j) {
                int row = row0 + rt * 16 + kg * 4 + j;
                if (row >= N) continue;
                QWb[(size_t)row * 64 + w * 16 + cc] = pack2(acc[rt][0][j], acc[rt][1][j]);
                unsigned char* kvrow = &KV[(size_t)row * 384];
                u32 kp = __builtin_amdgcn_cvt_pk_fp8_f32(acc[rt][2][j], acc[rt][3][j], 0u, false);
                *(u16*)&kvrow[w * 32 + cc * 2] = (u16)kp;
                *(u32*)&kvrow[128 + 4 * (w * 16 + cc)] = pack2(acc[rt][4][j], acc[rt][5][j]);
            }
        }
    }
}

// ---------------------------------------------------------------------------
// Aggregate: quarter-wave (16-lane) groups, 4 edges in flight/wave.
// Gathers interleaved KV (fp8 K + bf16 VPo); epilogue divides by z, adds bo,
// writes fp32 DIRECTLY to out (Wo pre-folded into VPo; out_mfma removed).
// Lane i slots 8i..8i+7 -> natural cols {base..base+3, base+16..base+19},
// base = 32(i>>2) + 4(i&3).
// ---------------------------------------------------------------------------
__global__ __launch_bounds__(256) void aggregate(
    const int* __restrict__ offs, const int* __restrict__ ssrc,
    const unsigned char* __restrict__ KV, const u32* __restrict__ QWb,
    const float* __restrict__ We2r, const float* __restrict__ be2,
    const float* __restrict__ bo, float* __restrict__ out, int N) {
    const int node = (blockIdx.x * 256 + threadIdx.x) >> 6;
    const int lane = threadIdx.x & 63;
    if (node >= N) return;
    const int g = lane >> 4, i = lane & 15;

    const float SC = 0.08838834764831845f * 1.4426950408889634f;  // (1/sqrt128)*log2e
    const float CL = 5.0f * 1.4426950408889634f;

    uint4 Qu = *(const uint4*)&QWb[(size_t)node * 64 + 4 * i];
    f32x2 q01 = {unlo(Qu.x), unhi(Qu.x)};
    f32x2 q23 = {unlo(Qu.y), unhi(Qu.y)};
    f32x2 q45 = {unlo(Qu.z), unhi(Qu.z)};
    f32x2 q67 = {unlo(Qu.w), unhi(Qu.w)};
    f32x2 w01 = *(const f32x2*)&We2r[8 * i];
    f32x2 w23 = *(const f32x2*)&We2r[8 * i + 2];
    f32x2 w45 = *(const f32x2*)&We2r[8 * i + 4];
    f32x2 w67 = *(const f32x2*)&We2r[8 * i + 6];
    const float B2SC = be2[0] * SC;
    const f32x2 zero2 = {0.f, 0.f};

    const int beg = offs[node], end = offs[node + 1];
    f32x2 acc01 = zero2, acc23 = zero2, acc45 = zero2, acc67 = zero2;
    float zacc = 0.f;

    int e = beg + g;
    int s = (e < end) ? ssrc[e] : 0;
    for (int e0 = beg; e0 < end; e0 += 4) {
        const bool act = (e0 + g) < end;
        const unsigned char* row = &KV[(size_t)s * 384];
        uint2 kk = *(const uint2*)&row[8 * i];
        uint4 vv = *(const uint4*)&row[128 + 16 * i];
        int en = e0 + 4 + g;
        s = (en < end) ? ssrc[en] : 0;  // prefetch next group edge index

        f32x2 d, p2;
        d = __builtin_amdgcn_cvt_pk_f32_fp8(kk.x, false) - q01;
        d = __builtin_elementwise_max(d, zero2);
        p2 = d * w01;
        d = __builtin_amdgcn_cvt_pk_f32_fp8(kk.x, true) - q23;
        d = __builtin_elementwise_max(d, zero2);
        p2 += d * w23;
        d = __builtin_amdgcn_cvt_pk_f32_fp8(kk.y, false) - q45;
        d = __builtin_elementwise_max(d, zero2);
        p2 += d * w45;
        d = __builtin_amdgcn_cvt_pk_f32_fp8(kk.y, true) - q67;
        d = __builtin_elementwise_max(d, zero2);
        p2 += d * w67;
        float p = p2[0] + p2[1];
#pragma unroll
        for (int off = 1; off <= 8; off <<= 1) p += __shfl_xor(p, off);

        float targ = fmaf(p, SC, B2SC);
        targ = fminf(fmaxf(targ, -CL), CL);
        float sc = act ? exp2f(targ) : 0.f;
        f32x2 sc2 = {sc, sc};

        f32x2 v;
        v = (f32x2){unlo(vv.x), unhi(vv.x)}; acc01 += v * sc2;
        v = (f32x2){unlo(vv.y), unhi(vv.y)}; acc23 += v * sc2;
        v = (f32x2){unlo(vv.z), unhi(vv.z)}; acc45 += v * sc2;
        v = (f32x2){unlo(vv.w), unhi(vv.w)}; acc67 += v * sc2;
        zacc += sc;
    }

    float a0 = acc01[0], a1 = acc01[1], a2 = acc23[0], a3 = acc23[1];
    float a4 = acc45[0], a5 = acc45[1], a6 = acc67[0], a7 = acc67[1];

    // cross-group combine
    a0 += __shfl_xor(a0, 16); a0 += __shfl_xor(a0, 32);
    a1 += __shfl_xor(a1, 16); a1 += __shfl_xor(a1, 32);
    a2 += __shfl_xor(a2, 16); a2 += __shfl_xor(a2, 32);
    a3 += __shfl_xor(a3, 16); a3 += __shfl_xor(a3, 32);
    a4 += __shfl_xor(a4, 16); a4 += __shfl_xor(a4, 32);
    a5 += __shfl_xor(a5, 16); a5 += __shfl_xor(a5, 32);
    a6 += __shfl_xor(a6, 16); a6 += __shfl_xor(a6, 32);
    a7 += __shfl_xor(a7, 16); a7 += __shfl_xor(a7, 32);
    zacc += __shfl_xor(zacc, 16); zacc += __shfl_xor(zacc, 32);

    if (g == 0) {
        float rz = 1.0f / zacc;
        const int base = 32 * (i >> 2) + 4 * (i & 3);
        float4 bA = *(const float4*)&bo[base];
        float4 bB = *(const float4*)&bo[base + 16];
        // slots 8i+r: r even -> cols base+(r>>1); r odd -> cols base+16+(r>>1)
        float4 oA = make_float4(fmaf(a0, rz, bA.x), fmaf(a2, rz, bA.y),
                                fmaf(a4, rz, bA.z), fmaf(a6, rz, bA.w));
        float4 oB = make_float4(fmaf(a1, rz, bB.x), fmaf(a3, rz, bB.y),
                                fmaf(a5, rz, bB.z), fmaf(a7, rz, bB.w));
        float* orow = &out[(size_t)node * DD];
        *(float4*)&orow[base] = oA;
        *(float4*)&orow[base + 16] = oB;
    }
}

// ---------------------------------------------------------------------------
extern "C" void kernel_launch(void* const* d_in, const int* in_sizes, int n_in,
                              void* d_out, int out_size, void* d_ws, size_t ws_size,
                              hipStream_t stream) {
    const float* h   = (const float*)d_in[0];
    const float* c   = (const float*)d_in[1];
    const int*   src = (const int*)d_in[2];
    const int*   dst = (const int*)d_in[3];
    const float* Wq  = (const float*)d_in[4];
    const float* Wk  = (const float*)d_in[5];
    const float* Wv  = (const float*)d_in[6];
    const float* Wp1 = (const float*)d_in[7];
    const float* bp1 = (const float*)d_in[8];
    const float* Wp2 = (const float*)d_in[9];
    const float* bp2 = (const float*)d_in[10];
    const float* We1 = (const float*)d_in[11];
    const float* be1 = (const float*)d_in[12];
    const float* We2 = (const float*)d_in[13];
    const float* be2 = (const float*)d_in[14];
    const float* Wo  = (const float*)d_in[15];
    const float* bo  = (const float*)d_in[16];

    const int N = in_sizes[0] / DD;
    const int E = in_sizes[2];
    const int NR = (N + 511) >> 9;        // 512-node buckets
    const int NB1 = (E + 4095) / 4096;    // p1 blocks
    const int NG = (N + 63) / 64;         // GEMM blocks

    u32* BF    = (u32*)d_ws;                       // 120*256 u32
    u32* QWb   = BF + 120 * 256;                   // N*64 u32
    unsigned char* KV = (unsigned char*)(QWb + (size_t)N * 64);  // N*384 B
    int* offs  = (int*)(KV + (size_t)N * 384);     // NR*512+1
    int* gcount = offs + ((size_t)NR * 512 + 1);   // 256
    int* bbase  = gcount + 256;                    // 256
    float* We2r = (float*)(bbase + 256);           // 128
    int* ssrc   = (int*)(We2r + 128);              // E
    u32* ebuf   = (u32*)(ssrc + E);                // 256*CAP

    hipMemsetAsync(gcount, 0, 256 * sizeof(int), stream);

    fused_pre<<<30 + NB1, 256, 0, stream>>>(Wq, Wk, Wv, We1, be1, Wp2, bp2, Wo,
                                            BF, src, dst, gcount, ebuf, E);

    scanB_we2r<<<1, 256, 0, stream>>>(gcount, bbase, We2, We2r);

    fused_mid<<<NR + NG, 256, 0, stream>>>(
        h, c, Wp1, bp1, BF, QWb, KV, N,
        gcount, bbase, ebuf, ssrc, offs, E, NR);

    aggregate<<<(N * 64 + 255) / 256, 256, 0, stream>>>(
        offs, ssrc, KV, QWb, We2r, be2, bo, (float*)d_out, N);
}